// Round 2
// baseline (2119.374 us; speedup 1.0000x reference)
//
#include <hip/hip_runtime.h>
#include <hip/hip_bf16.h>

// Problem constants
#define NN 384            // sequence dim
#define CZ 128            // channels
#define NH 4              // heads
#define HD 32             // head dim
#define MROWS (NN*NN)     // 147456 GEMM rows

typedef __hip_bfloat16 bf16;

// bf16 <-> f32 helpers (bit-level, RNE) — avoids API/overload risk
__device__ __forceinline__ float b2f(unsigned short u) {
    return __uint_as_float(((unsigned)u) << 16);
}
__device__ __forceinline__ unsigned short f2b(float f) {
    unsigned u = __float_as_uint(f);
    return (unsigned short)((u + 0x7FFFu + ((u >> 16) & 1u)) >> 16);
}

// ---------------------------------------------------------------------------
// LayerNorm stats: one wave per row of 128; 4 rows per 256-thread block.
// Writes mu[r], rstd[r] only (LN itself is fused into downstream GEMMs).
// ---------------------------------------------------------------------------
__global__ __launch_bounds__(256) void ln_stats_kernel(const float* __restrict__ z,
                                                       float* __restrict__ mu,
                                                       float* __restrict__ rstd) {
    const int wave = threadIdx.x >> 6;
    const int lane = threadIdx.x & 63;
    const int r = blockIdx.x * 4 + wave;
    const float* zr = z + (size_t)r * CZ;
    float x0 = zr[lane], x1 = zr[lane + 64];
    float sum = x0 + x1;
    float sq  = x0 * x0 + x1 * x1;
    #pragma unroll
    for (int o = 32; o > 0; o >>= 1) {
        sum += __shfl_xor(sum, o, 64);
        sq  += __shfl_xor(sq,  o, 64);
    }
    if (lane == 0) {
        const float m   = sum * (1.0f / CZ);
        const float var = sq * (1.0f / CZ) - m * m;
        mu[r]   = m;
        rstd[r] = rsqrtf(var + 1e-5f);
    }
}

// ---------------------------------------------------------------------------
// qkv GEMM with fused LayerNorm on A: C = LN(z) @ qkv_w + qkv_b
// BM=64 BN=64 BK=32, 256 threads, 4x4 micro-tile. Output scattered as bf16
// into qkv_t[t][h][n][i][d] so attention reads are contiguous per (n,h).
// ---------------------------------------------------------------------------
__global__ __launch_bounds__(256) void qkv_gemm_kernel(const float* __restrict__ z,
                                                       const float* __restrict__ mu,
                                                       const float* __restrict__ rstd,
                                                       const float* __restrict__ lnw,
                                                       const float* __restrict__ lnb,
                                                       const float* __restrict__ W,
                                                       const float* __restrict__ bias,
                                                       bf16* __restrict__ qkv_t) {
    __shared__ float As[32][68];   // [k][row]
    __shared__ float Bs[32][68];   // [k][col]

    const int tid = threadIdx.x;
    const int tx = tid & 15;
    const int ty = tid >> 4;
    const int row0 = blockIdx.x * 64;
    const int col0 = blockIdx.y * 64;

    float acc[4][4];
    #pragma unroll
    for (int i = 0; i < 4; i++)
        #pragma unroll
        for (int j = 0; j < 4; j++) acc[i][j] = 0.0f;

    for (int kt = 0; kt < 128; kt += 32) {
        // A tile: LayerNorm fused at load
        #pragma unroll
        for (int l = tid; l < 512; l += 256) {
            const int ar = l >> 3;
            const int ac4 = l & 7;
            const int row = row0 + ar;
            const int c = kt + ac4 * 4;
            const float4 zv = *(const float4*)(z + (size_t)row * CZ + c);
            const float m  = mu[row];
            const float rs = rstd[row];
            const float4 w4 = *(const float4*)(lnw + c);
            const float4 b4 = *(const float4*)(lnb + c);
            As[ac4 * 4 + 0][ar] = (zv.x - m) * rs * w4.x + b4.x;
            As[ac4 * 4 + 1][ar] = (zv.y - m) * rs * w4.y + b4.y;
            As[ac4 * 4 + 2][ar] = (zv.z - m) * rs * w4.z + b4.z;
            As[ac4 * 4 + 3][ar] = (zv.w - m) * rs * w4.w + b4.w;
        }
        // B tile 32x64
        #pragma unroll
        for (int l = tid; l < 512; l += 256) {
            const int br = l >> 4;
            const int bc4 = l & 15;
            *(float4*)&Bs[br][bc4 * 4] =
                *(const float4*)(W + (size_t)(kt + br) * (3 * CZ) + col0 + bc4 * 4);
        }
        __syncthreads();
        #pragma unroll
        for (int kk = 0; kk < 32; kk++) {
            const float4 a4 = *(const float4*)&As[kk][ty * 4];
            const float4 b4 = *(const float4*)&Bs[kk][tx * 4];
            acc[0][0] += a4.x * b4.x; acc[0][1] += a4.x * b4.y; acc[0][2] += a4.x * b4.z; acc[0][3] += a4.x * b4.w;
            acc[1][0] += a4.y * b4.x; acc[1][1] += a4.y * b4.y; acc[1][2] += a4.y * b4.z; acc[1][3] += a4.y * b4.w;
            acc[2][0] += a4.z * b4.x; acc[2][1] += a4.z * b4.y; acc[2][2] += a4.z * b4.z; acc[2][3] += a4.z * b4.w;
            acc[3][0] += a4.w * b4.x; acc[3][1] += a4.w * b4.y; acc[3][2] += a4.w * b4.z; acc[3][3] += a4.w * b4.w;
        }
        __syncthreads();
    }

    // Epilogue: +bias, convert bf16, scatter to qkv_t[t][h][n][i][d]
    const int gr0 = row0 + ty * 4;     // GEMM row = i*NN + n
    const int gc  = col0 + tx * 4;     // GEMM col in [0,384)
    const float4 b4 = *(const float4*)(bias + gc);
    const int i  = gr0 / NN;
    const int n0 = gr0 - i * NN;
    const int t  = gc >> 7;
    const int hh = (gc & 127) >> 5;
    const int d0 = gc & 31;
    const size_t colbase = (size_t)((t * NH + hh) * NN) * (NN * HD) + (size_t)i * HD + d0;
    #pragma unroll
    for (int rr = 0; rr < 4; rr++) {
        const size_t idx = colbase + (size_t)(n0 + rr) * (NN * HD);
        ushort4 pk;
        pk.x = f2b(acc[rr][0] + b4.x);
        pk.y = f2b(acc[rr][1] + b4.y);
        pk.z = f2b(acc[rr][2] + b4.z);
        pk.w = f2b(acc[rr][3] + b4.w);
        *(ushort4*)(qkv_t + idx) = pk;
    }
}

// ---------------------------------------------------------------------------
// Attention per (n,h): S[i,j] = scale * q_i . k_j
// softmax over i (per-COLUMN j), O[i,:] = sum_j P[i,j] v[j,:]
// Phase 1: thread owns column j (k_j in regs), online m_j/s_j over i.
// Phase 2: thread owns row i (q_i in regs), k/v tiles staged through LDS.
// Output written directly into d_out (later consumed in-place by final GEMM).
// ---------------------------------------------------------------------------
__global__ __launch_bounds__(384) void attn_kernel(const bf16* __restrict__ qkv_t,
                                                   float* __restrict__ attn_out) {
    __shared__ float qs[32][NN];    // [d][i], pre-scaled   48 KB
    __shared__ float mst[NN];
    __shared__ float sst[NN];       // holds 1/s
    __shared__ float ks[32][32];
    __shared__ float vs[32][32];

    const int b = blockIdx.x;
    const int n = b >> 2;
    const int h = b & 3;
    const int tid = threadIdx.x;
    const size_t base_q = (size_t)((0 * NH + h) * NN + n) * (NN * HD);
    const size_t base_k = (size_t)((1 * NH + h) * NN + n) * (NN * HD);
    const size_t base_v = (size_t)((2 * NH + h) * NN + n) * (NN * HD);
    const float scale = 0.17677669529663687f;  // 1/sqrt(32)

    // q row `tid` (pre-scaled) transposed into qs[d][i]
    {
        const bf16* qp = qkv_t + base_q + (size_t)tid * HD;
        #pragma unroll
        for (int d4 = 0; d4 < 8; d4++) {
            const ushort4 u = *(const ushort4*)(qp + d4 * 4);
            qs[d4 * 4 + 0][tid] = b2f(u.x) * scale;
            qs[d4 * 4 + 1][tid] = b2f(u.y) * scale;
            qs[d4 * 4 + 2][tid] = b2f(u.z) * scale;
            qs[d4 * 4 + 3][tid] = b2f(u.w) * scale;
        }
    }
    // k_j into registers (j = tid)
    float kr[32];
    {
        const bf16* kp = qkv_t + base_k + (size_t)tid * HD;
        #pragma unroll
        for (int d4 = 0; d4 < 8; d4++) {
            const ushort4 u = *(const ushort4*)(kp + d4 * 4);
            kr[d4 * 4 + 0] = b2f(u.x); kr[d4 * 4 + 1] = b2f(u.y);
            kr[d4 * 4 + 2] = b2f(u.z); kr[d4 * 4 + 3] = b2f(u.w);
        }
    }
    __syncthreads();

    // ---- Phase 1: column stats (thread = column j) ----
    float m = -1e30f, s = 0.0f;
    for (int i4 = 0; i4 < NN / 4; i4++) {
        float S0 = 0.f, S1 = 0.f, S2 = 0.f, S3 = 0.f;
        #pragma unroll
        for (int d = 0; d < 32; d++) {
            const float4 q4 = *(const float4*)&qs[d][i4 * 4];
            S0 += q4.x * kr[d]; S1 += q4.y * kr[d];
            S2 += q4.z * kr[d]; S3 += q4.w * kr[d];
        }
        const float mx = fmaxf(fmaxf(S0, S1), fmaxf(S2, S3));
        const float mn = fmaxf(m, mx);
        const float c = __expf(m - mn);
        s = s * c + __expf(S0 - mn) + __expf(S1 - mn) + __expf(S2 - mn) + __expf(S3 - mn);
        m = mn;
    }
    mst[tid] = m;
    sst[tid] = 1.0f / s;

    // ---- Phase 2 prep: own q row into regs, O accumulator ----
    float qr[32];
    #pragma unroll
    for (int d = 0; d < 32; d++) qr[d] = qs[d][tid];
    float O[32];
    #pragma unroll
    for (int d = 0; d < 32; d++) O[d] = 0.0f;
    __syncthreads();   // mst/sst visible to all

    for (int jt = 0; jt < NN / 32; jt++) {
        // stage k/v tile (32 j x 32 d each, bf16 -> f32)
        for (int l = tid; l < 512; l += 384) {
            const int half = l >> 8;    // 0 = k, 1 = v
            const int li = l & 255;
            const int jj = li >> 3, c4 = li & 7;
            const ushort4 u = *(const ushort4*)(qkv_t + (half ? base_v : base_k) +
                                                (size_t)(jt * 32 + jj) * HD + c4 * 4);
            float* dp = half ? &vs[jj][c4 * 4] : &ks[jj][c4 * 4];
            dp[0] = b2f(u.x); dp[1] = b2f(u.y); dp[2] = b2f(u.z); dp[3] = b2f(u.w);
        }
        __syncthreads();
        #pragma unroll 4
        for (int jj = 0; jj < 32; jj++) {
            float S = 0.0f;
            #pragma unroll
            for (int d4 = 0; d4 < 8; d4++) {
                const float4 k4 = *(const float4*)&ks[jj][d4 * 4];
                S += qr[d4 * 4 + 0] * k4.x + qr[d4 * 4 + 1] * k4.y +
                     qr[d4 * 4 + 2] * k4.z + qr[d4 * 4 + 3] * k4.w;
            }
            const int j = jt * 32 + jj;
            const float w = __expf(S - mst[j]) * sst[j];
            #pragma unroll
            for (int d4 = 0; d4 < 8; d4++) {
                const float4 v4 = *(const float4*)&vs[jj][d4 * 4];
                O[d4 * 4 + 0] += w * v4.x; O[d4 * 4 + 1] += w * v4.y;
                O[d4 * 4 + 2] += w * v4.z; O[d4 * 4 + 3] += w * v4.w;
            }
        }
        __syncthreads();
    }

    // write O row: attn_out[(i*NN + n)*CZ + h*HD + d]
    float* op = attn_out + ((size_t)tid * NN + n) * CZ + h * HD;
    #pragma unroll
    for (int d4 = 0; d4 < 8; d4++) {
        *(float4*)(op + d4 * 4) = make_float4(O[d4 * 4 + 0], O[d4 * 4 + 1],
                                              O[d4 * 4 + 2], O[d4 * 4 + 3]);
    }
}

// ---------------------------------------------------------------------------
// Final dual GEMM, BM=64 BN=128 (block owns its 64 rows EXCLUSIVELY so the
// in-place read/overwrite of `out` is race-free):
//   gate = sigmoid(LN(z) @ gate_w + gate_b)     (LN fused via mu/rstd)
//   proj = attn   @ out_w  + out_b               (attn read from `out`)
//   out  = z + gate * proj                       (overwrites same rows)
// 256 threads, micro-tile 8 rows x 4 cols, two accumulator sets.
// ---------------------------------------------------------------------------
__global__ __launch_bounds__(256) void final_kernel(const float* __restrict__ z,
                                                    const float* __restrict__ mu,
                                                    const float* __restrict__ rstd,
                                                    const float* __restrict__ lnw,
                                                    const float* __restrict__ lnb,
                                                    const float* __restrict__ gate_w,
                                                    const float* __restrict__ gate_b,
                                                    const float* __restrict__ out_w,
                                                    const float* __restrict__ out_b,
                                                    float* __restrict__ out) {
    __shared__ float As1[32][68];   // LN(z)  [k][row]
    __shared__ float As2[32][68];   // attn   [k][row]
    __shared__ float Bs1[32][132];  // gate_w [k][col]
    __shared__ float Bs2[32][132];  // out_w  [k][col]

    const int tid = threadIdx.x;
    const int tx = tid & 31;        // col group (x4) -> 128 cols
    const int ty = tid >> 5;        // row group (x8) -> 64 rows
    const int row0 = blockIdx.x * 64;

    float acc1[8][4], acc2[8][4];
    #pragma unroll
    for (int i = 0; i < 8; i++)
        #pragma unroll
        for (int j = 0; j < 4; j++) { acc1[i][j] = 0.0f; acc2[i][j] = 0.0f; }

    for (int kt = 0; kt < 128; kt += 32) {
        // A tiles: LN(z) and attn(=out) rows
        #pragma unroll
        for (int l = tid; l < 512; l += 256) {
            const int ar = l >> 3;
            const int ac4 = l & 7;
            const int row = row0 + ar;
            const int c = kt + ac4 * 4;
            const size_t gi = (size_t)row * CZ + c;
            const float4 zv = *(const float4*)(z + gi);
            const float4 av = *(const float4*)(out + gi);
            const float m  = mu[row];
            const float rs = rstd[row];
            const float4 w4 = *(const float4*)(lnw + c);
            const float4 b4 = *(const float4*)(lnb + c);
            As1[ac4 * 4 + 0][ar] = (zv.x - m) * rs * w4.x + b4.x;
            As1[ac4 * 4 + 1][ar] = (zv.y - m) * rs * w4.y + b4.y;
            As1[ac4 * 4 + 2][ar] = (zv.z - m) * rs * w4.z + b4.z;
            As1[ac4 * 4 + 3][ar] = (zv.w - m) * rs * w4.w + b4.w;
            As2[ac4 * 4 + 0][ar] = av.x;
            As2[ac4 * 4 + 1][ar] = av.y;
            As2[ac4 * 4 + 2][ar] = av.z;
            As2[ac4 * 4 + 3][ar] = av.w;
        }
        // B tiles 32x128 each
        #pragma unroll
        for (int l = tid; l < 1024; l += 256) {
            const int br = l >> 5;
            const int bc4 = l & 31;
            const size_t gb = (size_t)(kt + br) * CZ + bc4 * 4;
            *(float4*)&Bs1[br][bc4 * 4] = *(const float4*)(gate_w + gb);
            *(float4*)&Bs2[br][bc4 * 4] = *(const float4*)(out_w + gb);
        }
        __syncthreads();
        #pragma unroll
        for (int kk = 0; kk < 32; kk++) {
            const float4 a1a = *(const float4*)&As1[kk][ty * 8];
            const float4 a1b = *(const float4*)&As1[kk][ty * 8 + 4];
            const float4 a2a = *(const float4*)&As2[kk][ty * 8];
            const float4 a2b = *(const float4*)&As2[kk][ty * 8 + 4];
            const float4 b1 = *(const float4*)&Bs1[kk][tx * 4];
            const float4 b2 = *(const float4*)&Bs2[kk][tx * 4];
            const float a1[8] = {a1a.x, a1a.y, a1a.z, a1a.w, a1b.x, a1b.y, a1b.z, a1b.w};
            const float a2[8] = {a2a.x, a2a.y, a2a.z, a2a.w, a2b.x, a2b.y, a2b.z, a2b.w};
            #pragma unroll
            for (int rr = 0; rr < 8; rr++) {
                acc1[rr][0] += a1[rr] * b1.x; acc1[rr][1] += a1[rr] * b1.y;
                acc1[rr][2] += a1[rr] * b1.z; acc1[rr][3] += a1[rr] * b1.w;
                acc2[rr][0] += a2[rr] * b2.x; acc2[rr][1] += a2[rr] * b2.y;
                acc2[rr][2] += a2[rr] * b2.z; acc2[rr][3] += a2[rr] * b2.w;
            }
        }
        __syncthreads();
    }

    // Epilogue: out = z + sigmoid(gate) * (proj + bias)  — overwrites own rows
    const int col = tx * 4;
    const float4 gb = *(const float4*)(gate_b + col);
    const float4 ob = *(const float4*)(out_b + col);
    #pragma unroll
    for (int rr = 0; rr < 8; rr++) {
        const int row = row0 + ty * 8 + rr;
        const size_t idx = (size_t)row * CZ + col;
        const float4 z4 = *(const float4*)(z + idx);
        float4 o;
        o.x = z4.x + (1.0f / (1.0f + __expf(-(acc1[rr][0] + gb.x)))) * (acc2[rr][0] + ob.x);
        o.y = z4.y + (1.0f / (1.0f + __expf(-(acc1[rr][1] + gb.y)))) * (acc2[rr][1] + ob.y);
        o.z = z4.z + (1.0f / (1.0f + __expf(-(acc1[rr][2] + gb.z)))) * (acc2[rr][2] + ob.z);
        o.w = z4.w + (1.0f / (1.0f + __expf(-(acc1[rr][3] + gb.w)))) * (acc2[rr][3] + ob.w);
        *(float4*)(out + idx) = o;
    }
}

// ---------------------------------------------------------------------------
extern "C" void kernel_launch(void* const* d_in, const int* in_sizes, int n_in,
                              void* d_out, int out_size, void* d_ws, size_t ws_size,
                              hipStream_t stream) {
    const float* z      = (const float*)d_in[0];
    const float* ln_w   = (const float*)d_in[1];
    const float* ln_b   = (const float*)d_in[2];
    const float* qkv_w  = (const float*)d_in[3];
    const float* qkv_b  = (const float*)d_in[4];
    const float* out_w  = (const float*)d_in[5];
    const float* out_b  = (const float*)d_in[6];
    const float* gate_w = (const float*)d_in[7];
    const float* gate_b = (const float*)d_in[8];
    float* out = (float*)d_out;

    // Workspace: mu(147456 f32) + rstd(147456 f32) + qkv_t(56.6M bf16) ~= 109 MiB
    float* ws = (float*)d_ws;
    float* mu_buf   = ws;
    float* rstd_buf = ws + MROWS;
    bf16*  qkv_t    = (bf16*)(ws + 2 * MROWS);

    // 1) LayerNorm stats
    ln_stats_kernel<<<MROWS / 4, 256, 0, stream>>>(z, mu_buf, rstd_buf);
    // 2) qkv GEMM (LN fused) -> bf16 qkv_t[t][h][n][i][d]
    qkv_gemm_kernel<<<dim3(MROWS / 64, 6), 256, 0, stream>>>(z, mu_buf, rstd_buf,
                                                             ln_w, ln_b, qkv_w, qkv_b, qkv_t);
    // 3) attention -> writes d_out (as scratch for attn output)
    attn_kernel<<<NN * NH, 384, 0, stream>>>(qkv_t, out);
    // 4) dual GEMM: gate (LN fused) + out-proj, epilogue in-place on d_out
    final_kernel<<<MROWS / 64, 256, 0, stream>>>(z, mu_buf, rstd_buf, ln_w, ln_b,
                                                 gate_w, gate_b, out_w, out_b, out);
}

// Round 5
// 618.345 us; speedup vs baseline: 3.4275x; 3.4275x over previous
//
#include <hip/hip_runtime.h>
#include <hip/hip_bf16.h>

// Problem constants
#define NN 384            // sequence dim
#define CZ 128            // channels
#define NH 4              // heads
#define HD 32             // head dim
#define MROWS (NN*NN)     // 147456 GEMM rows

typedef __hip_bfloat16 bf16;
typedef short bf16x8f __attribute__((ext_vector_type(8)));          // MFMA A/B operand (8 bf16)
typedef float f32x4 __attribute__((ext_vector_type(4)));            // MFMA C/D operand
typedef unsigned short u16x8 __attribute__((ext_vector_type(8)));   // staging store type

// bf16 <-> f32 helpers (bit-level, RNE)
__device__ __forceinline__ float b2f(unsigned short u) {
    return __uint_as_float(((unsigned)u) << 16);
}
__device__ __forceinline__ unsigned short f2b(float f) {
    unsigned u = __float_as_uint(f);
    return (unsigned short)((u + 0x7FFFu + ((u >> 16) & 1u)) >> 16);
}

// ---------------------------------------------------------------------------
// LayerNorm stats: one wave per row of 128; writes mu[r], rstd[r].
// ---------------------------------------------------------------------------
__global__ __launch_bounds__(256) void ln_stats_kernel(const float* __restrict__ z,
                                                       float* __restrict__ mu,
                                                       float* __restrict__ rstd) {
    const int wave = threadIdx.x >> 6;
    const int lane = threadIdx.x & 63;
    const int r = blockIdx.x * 4 + wave;
    const float* zr = z + (size_t)r * CZ;
    float x0 = zr[lane], x1 = zr[lane + 64];
    float sum = x0 + x1;
    float sq  = x0 * x0 + x1 * x1;
    #pragma unroll
    for (int o = 32; o > 0; o >>= 1) {
        sum += __shfl_xor(sum, o, 64);
        sq  += __shfl_xor(sq,  o, 64);
    }
    if (lane == 0) {
        const float m   = sum * (1.0f / CZ);
        const float var = sq * (1.0f / CZ) - m * m;
        mu[r]   = m;
        rstd[r] = rsqrtf(var + 1e-5f);
    }
}

// ---------------------------------------------------------------------------
// qkv GEMM with fused LayerNorm on A: C = LN(z) @ qkv_w + qkv_b
// Output scattered as bf16 into qkv_t[t][h][n][i][d].
// ---------------------------------------------------------------------------
__global__ __launch_bounds__(256) void qkv_gemm_kernel(const float* __restrict__ z,
                                                       const float* __restrict__ mu,
                                                       const float* __restrict__ rstd,
                                                       const float* __restrict__ lnw,
                                                       const float* __restrict__ lnb,
                                                       const float* __restrict__ W,
                                                       const float* __restrict__ bias,
                                                       unsigned short* __restrict__ qkv_t) {
    __shared__ float As[32][68];   // [k][row]
    __shared__ float Bs[32][68];   // [k][col]

    const int tid = threadIdx.x;
    const int tx = tid & 15;
    const int ty = tid >> 4;
    const int row0 = blockIdx.x * 64;
    const int col0 = blockIdx.y * 64;

    float acc[4][4];
    #pragma unroll
    for (int i = 0; i < 4; i++)
        #pragma unroll
        for (int j = 0; j < 4; j++) acc[i][j] = 0.0f;

    for (int kt = 0; kt < 128; kt += 32) {
        #pragma unroll
        for (int l = tid; l < 512; l += 256) {
            const int ar = l >> 3;
            const int ac4 = l & 7;
            const int row = row0 + ar;
            const int c = kt + ac4 * 4;
            const float4 zv = *(const float4*)(z + (size_t)row * CZ + c);
            const float m  = mu[row];
            const float rs = rstd[row];
            const float4 w4 = *(const float4*)(lnw + c);
            const float4 b4 = *(const float4*)(lnb + c);
            As[ac4 * 4 + 0][ar] = (zv.x - m) * rs * w4.x + b4.x;
            As[ac4 * 4 + 1][ar] = (zv.y - m) * rs * w4.y + b4.y;
            As[ac4 * 4 + 2][ar] = (zv.z - m) * rs * w4.z + b4.z;
            As[ac4 * 4 + 3][ar] = (zv.w - m) * rs * w4.w + b4.w;
        }
        #pragma unroll
        for (int l = tid; l < 512; l += 256) {
            const int br = l >> 4;
            const int bc4 = l & 15;
            *(float4*)&Bs[br][bc4 * 4] =
                *(const float4*)(W + (size_t)(kt + br) * (3 * CZ) + col0 + bc4 * 4);
        }
        __syncthreads();
        #pragma unroll
        for (int kk = 0; kk < 32; kk++) {
            const float4 a4 = *(const float4*)&As[kk][ty * 4];
            const float4 b4 = *(const float4*)&Bs[kk][tx * 4];
            acc[0][0] += a4.x * b4.x; acc[0][1] += a4.x * b4.y; acc[0][2] += a4.x * b4.z; acc[0][3] += a4.x * b4.w;
            acc[1][0] += a4.y * b4.x; acc[1][1] += a4.y * b4.y; acc[1][2] += a4.y * b4.z; acc[1][3] += a4.y * b4.w;
            acc[2][0] += a4.z * b4.x; acc[2][1] += a4.z * b4.y; acc[2][2] += a4.z * b4.z; acc[2][3] += a4.z * b4.w;
            acc[3][0] += a4.w * b4.x; acc[3][1] += a4.w * b4.y; acc[3][2] += a4.w * b4.z; acc[3][3] += a4.w * b4.w;
        }
        __syncthreads();
    }

    const int gr0 = row0 + ty * 4;     // GEMM row = i*NN + n
    const int gc  = col0 + tx * 4;     // GEMM col in [0,384)
    const float4 b4 = *(const float4*)(bias + gc);
    const int i  = gr0 / NN;
    const int n0 = gr0 - i * NN;
    const int t  = gc >> 7;
    const int hh = (gc & 127) >> 5;
    const int d0 = gc & 31;
    const size_t colbase = (size_t)((t * NH + hh) * NN) * (NN * HD) + (size_t)i * HD + d0;
    #pragma unroll
    for (int rr = 0; rr < 4; rr++) {
        const size_t idx = colbase + (size_t)(n0 + rr) * (NN * HD);
        ushort4 pk;
        pk.x = f2b(acc[rr][0] + b4.x);
        pk.y = f2b(acc[rr][1] + b4.y);
        pk.z = f2b(acc[rr][2] + b4.z);
        pk.w = f2b(acc[rr][3] + b4.w);
        *(ushort4*)(qkv_t + idx) = pk;
    }
}

// ---------------------------------------------------------------------------
// MFMA attention per (n,h). S[i,j]=scale*q_i.k_j; softmax over i (per-col j);
// O[i,:] = sum_j P[i,j] v[j,:].
// Pass 1: S tiles via mfma_16x16x32 (K=32=HD), col sums of exp -> 1/s_j.
// Pass 2: S^T tiles (A=K,B=Q) -> P written to per-wave LDS scratch -> read
//         back as PV A-frag; V pre-swizzled into B-frag layout with 1/s
//         folded in at staging (quartered to fit LDS).
// NOTE round-3/4 bug: staging used `s & 1535` as mod-1536 — 1536 is NOT a
// power of two, so Kf slots 512..1023 were never written (uninit LDS -> NaN).
// Fixed with explicit subtract.
// LDS: Qf 24K + Kf 24K + Vf 6K + sst 1.5K + Pscr 5K = 62.0 KB -> 2 blocks/CU.
// ---------------------------------------------------------------------------
__global__ __launch_bounds__(256) void attn_mfma_kernel(const unsigned short* __restrict__ qkv_t,
                                                        float* __restrict__ attn_out) {
    __shared__ unsigned short Qf[24 * 512];   // frag-order: tile*512 + lane*8
    __shared__ unsigned short Kf[24 * 512];
    __shared__ unsigned short Vf[3 * 2 * 512]; // [chunk_local][dhalf][lane*8]
    __shared__ float sst[NN];                  // 1/s_j
    __shared__ unsigned short Pscr[4][16][40]; // per-wave P tile, pitch 40

    const int b = blockIdx.x;
    const int n = b >> 2;
    const int h = b & 3;
    const int tid = threadIdx.x;
    const int w = tid >> 6;        // wave 0..3
    const int l = tid & 63;        // lane
    const int q = l >> 4;          // quad 0..3
    const int m = l & 15;          // low lane bits
    const size_t base_q = (size_t)((0 * NH + h) * NN + n) * (NN * HD);
    const size_t base_k = (size_t)((1 * NH + h) * NN + n) * (NN * HD);
    const size_t base_v = (size_t)((2 * NH + h) * NN + n) * (NN * HD);
    const float SCALE = 0.17677669529663687f;  // 1/sqrt(32)
    const f32x4 zero = {0.0f, 0.0f, 0.0f, 0.0f};

    // ---- Stage Q and K into fragment-order LDS (3072 16B slots) ----
    #pragma unroll
    for (int it = 0; it < 12; it++) {
        const int s = tid + it * 256;
        const int isK = s >= 1536;
        const int slot = isK ? (s - 1536) : s;   // FIX: 1536 is not pow2; & 1535 was wrong
        const int t  = slot >> 6;
        const int l2 = slot & 63;
        const int row = t * 16 + (l2 & 15);
        const int off8 = (l2 >> 4) * 8;
        const u16x8 raw = *(const u16x8*)(qkv_t + (isK ? base_k : base_q) +
                                         (size_t)row * HD + off8);
        unsigned short* dst = (isK ? Kf : Qf) + slot * 8;
        *(u16x8*)dst = raw;
    }
    __syncthreads();

    // ---- Pass 1: column sums of exp(scale*S) -> sst[j] = 1/s_j ----
    for (int tt = 0; tt < 6; tt++) {
        const int jt = w + 4 * tt;
        const bf16x8f kb = *(const bf16x8f*)&Kf[jt * 512 + l * 8];
        float s0 = 0.f, s1 = 0.f, s2 = 0.f, s3 = 0.f;
        for (int it = 0; it < 24; it++) {
            const bf16x8f qa = *(const bf16x8f*)&Qf[it * 512 + l * 8];
            const f32x4 c = __builtin_amdgcn_mfma_f32_16x16x32_bf16(qa, kb, zero, 0, 0, 0);
            s0 += __expf(c[0] * SCALE);
            s1 += __expf(c[1] * SCALE);
            s2 += __expf(c[2] * SCALE);
            s3 += __expf(c[3] * SCALE);
        }
        float s = s0 + s1 + s2 + s3;
        s += __shfl_xor(s, 16, 64);
        s += __shfl_xor(s, 32, 64);
        if (q == 0) sst[jt * 16 + m] = 1.0f / s;
    }
    __syncthreads();

    // ---- Pass 2: O = P @ V' (V' = V * 1/s), V staged in quarters ----
    f32x4 oacc[6][2];
    #pragma unroll
    for (int tt = 0; tt < 6; tt++) {
        oacc[tt][0] = zero;
        oacc[tt][1] = zero;
    }

    for (int vr = 0; vr < 4; vr++) {
        // stage Vf: 384 slots (3 chunks x 2 dhalves x 64 lanes)
        for (int s = tid; s < 384; s += 256) {
            const int cl = s >> 7;           // 0..2
            const int dh = (s >> 6) & 1;
            const int l2 = s & 63;
            const int cg = vr * 3 + cl;
            const int j0 = cg * 32 + (l2 >> 4) * 8;
            const int d  = dh * 16 + (l2 & 15);
            ushort4 pk0, pk1;
            {
                const unsigned short* vp = qkv_t + base_v + (size_t)j0 * HD + d;
                pk0.x = f2b(b2f(vp[0 * HD]) * sst[j0 + 0]);
                pk0.y = f2b(b2f(vp[1 * HD]) * sst[j0 + 1]);
                pk0.z = f2b(b2f(vp[2 * HD]) * sst[j0 + 2]);
                pk0.w = f2b(b2f(vp[3 * HD]) * sst[j0 + 3]);
                pk1.x = f2b(b2f(vp[4 * HD]) * sst[j0 + 4]);
                pk1.y = f2b(b2f(vp[5 * HD]) * sst[j0 + 5]);
                pk1.z = f2b(b2f(vp[6 * HD]) * sst[j0 + 6]);
                pk1.w = f2b(b2f(vp[7 * HD]) * sst[j0 + 7]);
            }
            unsigned short* dst = Vf + ((cl * 2 + dh) * 64 + l2) * 8;
            *(ushort4*)(dst)     = pk0;
            *(ushort4*)(dst + 4) = pk1;
        }
        __syncthreads();

        for (int cl = 0; cl < 3; cl++) {
            const int cg = vr * 3 + cl;
            const bf16x8f ka0 = *(const bf16x8f*)&Kf[(cg * 2 + 0) * 512 + l * 8];
            const bf16x8f ka1 = *(const bf16x8f*)&Kf[(cg * 2 + 1) * 512 + l * 8];
            const bf16x8f vb0 = *(const bf16x8f*)&Vf[((cl * 2 + 0) * 64 + l) * 8];
            const bf16x8f vb1 = *(const bf16x8f*)&Vf[((cl * 2 + 1) * 64 + l) * 8];
            #pragma unroll
            for (int tt = 0; tt < 6; tt++) {
                const int it = w + 4 * tt;
                const bf16x8f qb = *(const bf16x8f*)&Qf[it * 512 + l * 8];
                // S^T tiles: rows j (quad*4+reg), cols i (m)
                const f32x4 sT0 = __builtin_amdgcn_mfma_f32_16x16x32_bf16(ka0, qb, zero, 0, 0, 0);
                const f32x4 sT1 = __builtin_amdgcn_mfma_f32_16x16x32_bf16(ka1, qb, zero, 0, 0, 0);
                // P = exp(scale*S): lane (q,m) holds P[i=m][j=q*4+r] (+16 for sT1)
                ushort4 p0, p1;
                p0.x = f2b(__expf(sT0[0] * SCALE));
                p0.y = f2b(__expf(sT0[1] * SCALE));
                p0.z = f2b(__expf(sT0[2] * SCALE));
                p0.w = f2b(__expf(sT0[3] * SCALE));
                p1.x = f2b(__expf(sT1[0] * SCALE));
                p1.y = f2b(__expf(sT1[1] * SCALE));
                p1.z = f2b(__expf(sT1[2] * SCALE));
                p1.w = f2b(__expf(sT1[3] * SCALE));
                *(ushort4*)&Pscr[w][m][q * 4]      = p0;
                *(ushort4*)&Pscr[w][m][16 + q * 4] = p1;
                // Same-wave LDS RAW (cross-lane within wave): fence + drain.
                __asm__ volatile("" ::: "memory");
                __builtin_amdgcn_s_waitcnt(0xC07F);   // lgkmcnt(0), vm/exp don't-care
                // read back as PV A-frag: P[i=m][j=q*8..q*8+7]
                const bf16x8f pa = *(const bf16x8f*)&Pscr[w][m][q * 8];
                __asm__ volatile("" ::: "memory");
                oacc[tt][0] = __builtin_amdgcn_mfma_f32_16x16x32_bf16(pa, vb0, oacc[tt][0], 0, 0, 0);
                oacc[tt][1] = __builtin_amdgcn_mfma_f32_16x16x32_bf16(pa, vb1, oacc[tt][1], 0, 0, 0);
            }
        }
        __syncthreads();
    }

    // ---- Store O: rows i = it*16 + q*4 + r, col d = dt*16 + m ----
    #pragma unroll
    for (int tt = 0; tt < 6; tt++) {
        const int it = w + 4 * tt;
        #pragma unroll
        for (int dt = 0; dt < 2; dt++) {
            #pragma unroll
            for (int r = 0; r < 4; r++) {
                const int i = it * 16 + q * 4 + r;
                attn_out[((size_t)i * NN + n) * CZ + h * HD + dt * 16 + m] = oacc[tt][dt][r];
            }
        }
    }
}

// ---------------------------------------------------------------------------
// Final dual GEMM (block owns 64 rows exclusively; in-place on out):
//   out = z + sigmoid(LN(z)@gate_w+gate_b) * (attn@out_w + out_b)
// ---------------------------------------------------------------------------
__global__ __launch_bounds__(256) void final_kernel(const float* __restrict__ z,
                                                    const float* __restrict__ mu,
                                                    const float* __restrict__ rstd,
                                                    const float* __restrict__ lnw,
                                                    const float* __restrict__ lnb,
                                                    const float* __restrict__ gate_w,
                                                    const float* __restrict__ gate_b,
                                                    const float* __restrict__ out_w,
                                                    const float* __restrict__ out_b,
                                                    float* __restrict__ out) {
    __shared__ float As1[32][68];
    __shared__ float As2[32][68];
    __shared__ float Bs1[32][132];
    __shared__ float Bs2[32][132];

    const int tid = threadIdx.x;
    const int tx = tid & 31;
    const int ty = tid >> 5;
    const int row0 = blockIdx.x * 64;

    float acc1[8][4], acc2[8][4];
    #pragma unroll
    for (int i = 0; i < 8; i++)
        #pragma unroll
        for (int j = 0; j < 4; j++) { acc1[i][j] = 0.0f; acc2[i][j] = 0.0f; }

    for (int kt = 0; kt < 128; kt += 32) {
        #pragma unroll
        for (int l = tid; l < 512; l += 256) {
            const int ar = l >> 3;
            const int ac4 = l & 7;
            const int row = row0 + ar;
            const int c = kt + ac4 * 4;
            const size_t gi = (size_t)row * CZ + c;
            const float4 zv = *(const float4*)(z + gi);
            const float4 av = *(const float4*)(out + gi);
            const float m  = mu[row];
            const float rs = rstd[row];
            const float4 w4 = *(const float4*)(lnw + c);
            const float4 b4 = *(const float4*)(lnb + c);
            As1[ac4 * 4 + 0][ar] = (zv.x - m) * rs * w4.x + b4.x;
            As1[ac4 * 4 + 1][ar] = (zv.y - m) * rs * w4.y + b4.y;
            As1[ac4 * 4 + 2][ar] = (zv.z - m) * rs * w4.z + b4.z;
            As1[ac4 * 4 + 3][ar] = (zv.w - m) * rs * w4.w + b4.w;
            As2[ac4 * 4 + 0][ar] = av.x;
            As2[ac4 * 4 + 1][ar] = av.y;
            As2[ac4 * 4 + 2][ar] = av.z;
            As2[ac4 * 4 + 3][ar] = av.w;
        }
        #pragma unroll
        for (int l = tid; l < 1024; l += 256) {
            const int br = l >> 5;
            const int bc4 = l & 31;
            const size_t gb = (size_t)(kt + br) * CZ + bc4 * 4;
            *(float4*)&Bs1[br][bc4 * 4] = *(const float4*)(gate_w + gb);
            *(float4*)&Bs2[br][bc4 * 4] = *(const float4*)(out_w + gb);
        }
        __syncthreads();
        #pragma unroll
        for (int kk = 0; kk < 32; kk++) {
            const float4 a1a = *(const float4*)&As1[kk][ty * 8];
            const float4 a1b = *(const float4*)&As1[kk][ty * 8 + 4];
            const float4 a2a = *(const float4*)&As2[kk][ty * 8];
            const float4 a2b = *(const float4*)&As2[kk][ty * 8 + 4];
            const float4 b1 = *(const float4*)&Bs1[kk][tx * 4];
            const float4 b2 = *(const float4*)&Bs2[kk][tx * 4];
            const float a1[8] = {a1a.x, a1a.y, a1a.z, a1a.w, a1b.x, a1b.y, a1b.z, a1b.w};
            const float a2[8] = {a2a.x, a2a.y, a2a.z, a2a.w, a2b.x, a2b.y, a2b.z, a2b.w};
            #pragma unroll
            for (int rr = 0; rr < 8; rr++) {
                acc1[rr][0] += a1[rr] * b1.x; acc1[rr][1] += a1[rr] * b1.y;
                acc1[rr][2] += a1[rr] * b1.z; acc1[rr][3] += a1[rr] * b1.w;
                acc2[rr][0] += a2[rr] * b2.x; acc2[rr][1] += a2[rr] * b2.y;
                acc2[rr][2] += a2[rr] * b2.z; acc2[rr][3] += a2[rr] * b2.w;
            }
        }
        __syncthreads();
    }

    const int col = tx * 4;
    const float4 gb = *(const float4*)(gate_b + col);
    const float4 ob = *(const float4*)(out_b + col);
    #pragma unroll
    for (int rr = 0; rr < 8; rr++) {
        const int row = row0 + ty * 8 + rr;
        const size_t idx = (size_t)row * CZ + col;
        const float4 z4 = *(const float4*)(z + idx);
        float4 o;
        o.x = z4.x + (1.0f / (1.0f + __expf(-(acc1[rr][0] + gb.x)))) * (acc2[rr][0] + ob.x);
        o.y = z4.y + (1.0f / (1.0f + __expf(-(acc1[rr][1] + gb.y)))) * (acc2[rr][1] + ob.y);
        o.z = z4.z + (1.0f / (1.0f + __expf(-(acc1[rr][2] + gb.z)))) * (acc2[rr][2] + ob.z);
        o.w = z4.w + (1.0f / (1.0f + __expf(-(acc1[rr][3] + gb.w)))) * (acc2[rr][3] + ob.w);
        *(float4*)(out + idx) = o;
    }
}

// ---------------------------------------------------------------------------
extern "C" void kernel_launch(void* const* d_in, const int* in_sizes, int n_in,
                              void* d_out, int out_size, void* d_ws, size_t ws_size,
                              hipStream_t stream) {
    const float* z      = (const float*)d_in[0];
    const float* ln_w   = (const float*)d_in[1];
    const float* ln_b   = (const float*)d_in[2];
    const float* qkv_w  = (const float*)d_in[3];
    const float* qkv_b  = (const float*)d_in[4];
    const float* out_w  = (const float*)d_in[5];
    const float* out_b  = (const float*)d_in[6];
    const float* gate_w = (const float*)d_in[7];
    const float* gate_b = (const float*)d_in[8];
    float* out = (float*)d_out;

    // Workspace: mu + rstd (f32) + qkv_t (bf16) ~= 109 MiB
    float* ws = (float*)d_ws;
    float* mu_buf   = ws;
    float* rstd_buf = ws + MROWS;
    unsigned short* qkv_t = (unsigned short*)(ws + 2 * MROWS);

    ln_stats_kernel<<<MROWS / 4, 256, 0, stream>>>(z, mu_buf, rstd_buf);
    qkv_gemm_kernel<<<dim3(MROWS / 64, 6), 256, 0, stream>>>(z, mu_buf, rstd_buf,
                                                             ln_w, ln_b, qkv_w, qkv_b, qkv_t);
    attn_mfma_kernel<<<NN * NH, 256, 0, stream>>>(qkv_t, out);
    final_kernel<<<MROWS / 64, 256, 0, stream>>>(z, mu_buf, rstd_buf, ln_w, ln_b,
                                                 gate_w, gate_b, out_w, out_b, out);
}